// Round 18
// baseline (306.936 us; speedup 1.0000x reference)
//
#include <hip/hip_runtime.h>
#include <hip/hip_bf16.h>
#include <cstdint>
#include <cstddef>

typedef float  f32x4  __attribute__((ext_vector_type(4)));
typedef __bf16 bf16x8 __attribute__((ext_vector_type(8)));
typedef __bf16 bf16x4 __attribute__((ext_vector_type(4)));

#define N_TOK  8192
#define INDIM  1024
#define DMODEL 512
#define NHALF  4096   // key-split half for P materialization

__device__ __forceinline__ f32x4 mfma16x16x32(bf16x8 a, bf16x8 b, f32x4 c){
  return __builtin_amdgcn_mfma_f32_16x16x32_bf16(a, b, c, 0, 0, 0);
}

__device__ __forceinline__ void async_copy16(void* lds, const void* g){
  __builtin_amdgcn_global_load_lds((__attribute__((address_space(1))) void*)g,
                                   (__attribute__((address_space(3))) void*)lds,
                                   16, 0, 0);
}

// ---------------- convert / transpose / bias-concat ----------------
__global__ void k_cvt(const float* __restrict__ in, __bf16* __restrict__ out, int n4){
  int stride = gridDim.x * blockDim.x;
  for (int i = blockIdx.x * blockDim.x + threadIdx.x; i < n4; i += stride){
    f32x4 v = ((const f32x4*)in)[i];
    bf16x4 o;
    o[0]=(__bf16)v[0]; o[1]=(__bf16)v[1]; o[2]=(__bf16)v[2]; o[3]=(__bf16)v[3];
    ((bf16x4*)out)[i] = o;
  }
}

__global__ void k_tcvt(const float* __restrict__ W, __bf16* __restrict__ Wt, int Kd, int Nd){
  int total = Kd * Nd;
  int stride = gridDim.x * blockDim.x;
  for (int i = blockIdx.x * blockDim.x + threadIdx.x; i < total; i += stride){
    int k = i / Nd, n = i - k * Nd;
    Wt[(size_t)n * Kd + k] = (__bf16)W[i];
  }
}

__global__ void k_bias2(const float* __restrict__ a, const float* __restrict__ b,
                        float* __restrict__ o){
  int idx = blockIdx.x * 256 + threadIdx.x;   // 0..1023
  o[idx] = (idx < 512) ? a[idx] : b[idx - 512];
}

// ---------------- generalized GEMM: C[M,N] = A[M,K-chunk] @ Bt^T ------------
// 256x128 tile, 512 threads (8 waves), BK=32, double-buffered 2-phase.
// Per-wave: same acc[4][4] m97 shape (wr=w>>1 m-strip, wc=w&1 n-strip)
// -> 16 waves/CU at the 2-blocks/CU register quantum (vs 8 for 4-wave blocks).
// LDS 48KB, 16B-slot swizzle key (row>>1)&3: linear gload dest + pre-swizzled
// source + swizzled ds_read (2-way max, free).
// EPI: 0 = +bias[col]; 2 = exp(scale*acc); 3 = plain.
// MAP: 0 = (x=m, y=n, z=K-chunk); 1 = xcd-chunked m (grid 1024, pexp);
//      2 = z = xcd>>2 (grid 256, PV).
// RSUM: fused per-(colblock,row) partial row sums from acc (deterministic).
template<int EPI, int MAP, int RSUM>
__global__ __launch_bounds__(512) void k_gemm(
    const __bf16* __restrict__ A, const __bf16* __restrict__ Bt,
    const float* __restrict__ bias, __bf16* __restrict__ C,
    int M, int N, int K, int lda, int ldb, int ldc, float scale,
    float* __restrict__ rsp, int rbase)
{
  __shared__ __bf16 Als[2][256*32];   // 16 KB per buf
  __shared__ __bf16 Bls[2][128*32];   // 8 KB per buf
  const int tid = threadIdx.x;
  const int w = tid >> 6, l = tid & 63;
  const int lr = l & 15, lg = l >> 4;
  const int wr = w >> 1, wc = w & 1;
  int m0, n0, kz, zsel;
  if (MAP == 0){
    m0 = blockIdx.x * 256; n0 = blockIdx.y * 128; zsel = blockIdx.z; kz = zsel * K;
  } else if (MAP == 1){
    // 1024 blocks: xcd-chunked m (4 m-tiles/XCD = 1024 rows L2-resident), n inner
    int lin = blockIdx.x, xcd = lin & 7, idx = lin >> 3;
    m0 = (xcd*4 + (idx & 3)) * 256; n0 = (idx >> 2) * 128; zsel = 0; kz = 0;
  } else {
    // 256 blocks: z = xcd>>2 (L2-resident B z-slice), n innermost
    int lin = blockIdx.x, xcd = lin & 7, i = lin >> 3;
    zsel = xcd >> 2; kz = zsel * K;
    m0 = ((xcd & 3)*8 + (i >> 2)) * 256; n0 = (i & 3) * 128;
  }
  // stage: chunk c (16B) -> dest byte c*16; row=c>>2, slot=c&3.
  // source col pre-swizzled by key (row>>1)&3 == (l>>3)&3 for our chunk maps.
  const int scol = ((l & 3) ^ ((l >> 3) & 3)) * 8;

  auto stage = [&](int b, int kk){
    // A: 1024 chunks = 2 wave-instrs each; chunk c = (i*8+w)*64 + l
    #pragma unroll
    for (int i = 0; i < 2; ++i){
      int rowb = (i*8 + w) * 16 + (l >> 2);           // c>>2
      async_copy16((char*)&Als[b][0] + (i*8 + w) * 1024,
                   A + (size_t)(m0 + rowb) * lda + kk + scol);
    }
    // B: 512 chunks = 1 wave-instr; chunk c = w*64 + l
    {
      int rowb = w * 16 + (l >> 2);
      async_copy16((char*)&Bls[b][0] + w * 1024,
                   Bt + (size_t)(n0 + rowb) * ldb + kk + scol);
    }
  };

  f32x4 acc[4][4] = {};
  const int nt = K >> 5;
  stage(0, kz);
  __syncthreads();
  const int cs = (lg ^ ((lr >> 1) & 3)) * 8;   // swizzled 16B read slot
  for (int t = 0; t < nt; ++t){
    const int cur = t & 1;
    if (t + 1 < nt) stage(cur ^ 1, kz + (t+1)*32);   // issue-early
    bf16x8 af[4], bfv[4];
    #pragma unroll
    for (int mf = 0; mf < 4; ++mf)
      af[mf]  = *(const bf16x8*)&Als[cur][(wr*64 + mf*16 + lr)*32 + cs];
    #pragma unroll
    for (int nf = 0; nf < 4; ++nf)
      bfv[nf] = *(const bf16x8*)&Bls[cur][(wc*64 + nf*16 + lr)*32 + cs];
    #pragma unroll
    for (int mf = 0; mf < 4; ++mf)
      #pragma unroll
      for (int nf = 0; nf < 4; ++nf)
        acc[mf][nf] = mfma16x16x32(af[mf], bfv[nf], acc[mf][nf]);
    __syncthreads();   // drains stage (issued a full phase earlier) + reads
  }
  // ---- epilogue: direct scattered stores + optional fused row sums ----
  __bf16* Cd = C + (size_t)zsel * (size_t)M * ldc;
  float rsp4[4][4];
  #pragma unroll
  for (int mf = 0; mf < 4; ++mf)
    #pragma unroll
    for (int r = 0; r < 4; ++r) rsp4[mf][r] = 0.0f;
  #pragma unroll
  for (int mf = 0; mf < 4; ++mf)
    #pragma unroll
    for (int nf = 0; nf < 4; ++nf)
      #pragma unroll
      for (int r = 0; r < 4; ++r){
        int row = m0 + wr*64 + mf*16 + lg*4 + r;
        int col = n0 + wc*64 + nf*16 + lr;
        float v = acc[mf][nf][r];
        if (EPI == 0) v += bias[col];
        if (EPI == 2) v = __expf(v * scale);
        Cd[(size_t)row * ldc + col] = (__bf16)v;
        if (RSUM) rsp4[mf][r] += v;
      }
  if (RSUM){
    #pragma unroll
    for (int mf = 0; mf < 4; ++mf)
      #pragma unroll
      for (int r = 0; r < 4; ++r)
        #pragma unroll
        for (int dl = 1; dl < 16; dl <<= 1)
          rsp4[mf][r] += __shfl_xor(rsp4[mf][r], dl);
    if (lr == 0){
      int cb = rbase + (n0 >> 6) + wc;
      #pragma unroll
      for (int mf = 0; mf < 4; ++mf)
        #pragma unroll
        for (int r = 0; r < 4; ++r)
          rsp[(size_t)cb * N_TOK + m0 + wr*64 + mf*16 + lg*4 + r] = rsp4[mf][r];
    }
  }
}

// ---------------- rs[row] = sum of 128 rsp partials ----------------
__global__ __launch_bounds__(256) void k_rsum(
    const float* __restrict__ rsp, float* __restrict__ rs)
{
  int row = blockIdx.x * 256 + threadIdx.x;   // 8192
  float s = 0.0f;
  #pragma unroll 8
  for (int j = 0; j < 128; ++j) s += rsp[(size_t)j * N_TOK + row];
  rs[row] = s;
}

// ---------------- V-projection split-K combine: vtb = p0 + p1 + bv[row] -----
__global__ __launch_bounds__(256) void k_vcomb(
    const __bf16* __restrict__ p, const float* __restrict__ bv,
    __bf16* __restrict__ vtb)
{
  int idx = blockIdx.x * 256 + threadIdx.x;   // 512*8192/8
  int row = idx >> 10;
  float b = bv[row];
  bf16x8 a = ((const bf16x8*)p)[idx];
  bf16x8 c = ((const bf16x8*)(p + (size_t)DMODEL * N_TOK))[idx];
  bf16x8 o;
  #pragma unroll
  for (int i = 0; i < 8; ++i)
    o[i] = (__bf16)((float)a[i] + (float)c[i] + b);
  ((bf16x8*)vtb)[idx] = o;
}

// ---------------- MLP head (fused 4-partial combine + GEMM + reduce) --------
__global__ __launch_bounds__(256) void k_mlp(
    const __bf16* __restrict__ p00, const __bf16* __restrict__ p01,
    const __bf16* __restrict__ p10, const __bf16* __restrict__ p11,
    const float* __restrict__ rs, const __bf16* __restrict__ W1t,
    const float* __restrict__ b1, const float* __restrict__ W2,
    const float* __restrict__ b2, float* __restrict__ out)
{
  __shared__ __bf16 Als[64][512];
  __shared__ float  red[4][64];
  const int tid = threadIdx.x;
  const int w = tid >> 6, l = tid & 63;
  const int lr = l & 15, lg = l >> 4;
  const int m0 = blockIdx.x * 64;
  #pragma unroll
  for (int i = 0; i < 16; ++i){
    int chunk = i*256 + tid;            // 0..4095
    int rl = chunk >> 6, c8 = chunk & 63;
    size_t off = (size_t)(m0 + rl) * 64 + c8;
    float inv = 1.0f / rs[m0 + rl];
    bf16x8 a = ((const bf16x8*)p00)[off];
    bf16x8 b = ((const bf16x8*)p01)[off];
    bf16x8 c = ((const bf16x8*)p10)[off];
    bf16x8 d = ((const bf16x8*)p11)[off];
    bf16x8 o;
    #pragma unroll
    for (int j = 0; j < 8; ++j)
      o[j] = (__bf16)((((float)a[j] + (float)b[j]) + ((float)c[j] + (float)d[j])) * inv);
    *(bf16x8*)&Als[rl][c8*8] = o;
  }
  __syncthreads();
  f32x4 acc[4][4] = {};
  for (int t = 0; t < 16; ++t){
    bf16x8 af[4];
    #pragma unroll
    for (int mf2 = 0; mf2 < 4; ++mf2) af[mf2] = *(const bf16x8*)&Als[mf2*16 + lr][t*32 + lg*8];
    #pragma unroll
    for (int nf2 = 0; nf2 < 4; ++nf2){
      bf16x8 bfr = *(const bf16x8*)&W1t[(size_t)(w*64 + nf2*16 + lr)*DMODEL + t*32 + lg*8];
      #pragma unroll
      for (int mf2 = 0; mf2 < 4; ++mf2)
        acc[mf2][nf2] = mfma16x16x32(af[mf2], bfr, acc[mf2][nf2]);
    }
  }
  float part[4][4] = {};
  #pragma unroll
  for (int nf2 = 0; nf2 < 4; ++nf2){
    int col = w*64 + nf2*16 + lr;
    float bb = b1[col], w2v = W2[col];
    #pragma unroll
    for (int mf2 = 0; mf2 < 4; ++mf2)
      #pragma unroll
      for (int r = 0; r < 4; ++r){
        float h = acc[mf2][nf2][r] + bb;
        h = h > 0.0f ? h : 0.0f;
        part[mf2][r] += h * w2v;
      }
  }
  #pragma unroll
  for (int mf2 = 0; mf2 < 4; ++mf2)
    #pragma unroll
    for (int r = 0; r < 4; ++r)
      #pragma unroll
      for (int dl = 1; dl < 16; dl <<= 1)
        part[mf2][r] += __shfl_xor(part[mf2][r], dl);
  if (lr == 0){
    #pragma unroll
    for (int mf2 = 0; mf2 < 4; ++mf2)
      #pragma unroll
      for (int r = 0; r < 4; ++r)
        red[w][mf2*16 + lg*4 + r] = part[mf2][r];
  }
  __syncthreads();
  if (tid < 64)
    out[m0 + tid] = red[0][tid] + red[1][tid] + red[2][tid] + red[3][tid] + b2[0];
}

// ---------------- launcher ----------------
extern "C" void kernel_launch(void* const* d_in, const int* in_sizes, int n_in,
                              void* d_out, int out_size, void* d_ws, size_t ws_size,
                              hipStream_t stream)
{
  const float* x  = (const float*)d_in[0];
  const float* Wq = (const float*)d_in[1];
  const float* bq = (const float*)d_in[2];
  const float* Wk = (const float*)d_in[3];
  const float* bk = (const float*)d_in[4];
  const float* Wv = (const float*)d_in[5];
  const float* bv = (const float*)d_in[6];
  const float* W1 = (const float*)d_in[7];
  const float* b1 = (const float*)d_in[8];
  const float* W2 = (const float*)d_in[9];
  const float* b2 = (const float*)d_in[10];
  float* out = (float*)d_out;
  char* ws = (char*)d_ws;
  // workspace layout
  __bf16* xb   = (__bf16*)(ws + 0);          // 16 MB (dead after V GEMM)
  __bf16* qkb  = (__bf16*)(ws + 16777216);   // 16 MB [8192][1024] rows [q|k]
  __bf16* vtb  = (__bf16*)(ws + 33554432);   // 8 MB  V^T [512][8192]
  __bf16* wqkt = (__bf16*)(ws + 50331648);   // 2 MB  [Wq^T ; Wk^T]
  __bf16* wvt  = (__bf16*)(ws + 52428800);   // 1 MB
  __bf16* w1t  = (__bf16*)(ws + 53477376);   // 0.25 MB -> ends 53739520
  float*  rs   = (float*)(ws + 53739520);    // 32 KB
  float*  bqk  = (float*)(ws + 53772288);    // 4 KB
  float*  rsp  = (float*)(ws + 54525952);    // 4 MB  [128][8192] partial row sums
  __bf16* Ph   = (__bf16*)(ws + 58720256);   // 64 MB  P half [8192][4096]
  __bf16* vpp  = (__bf16*)(ws + 58720256);   // V-proj partials (Ph region, early)
  // PV split-K partials (dead-region reuse)
  __bf16* p00  = (__bf16*)(ws + 0);          // xb region
  __bf16* p01  = (__bf16*)(ws + 8388608);
  __bf16* p10  = (__bf16*)(ws + 16777216);   // qkb region (dead after pexp1)
  __bf16* p11  = (__bf16*)(ws + 25165824);

  k_cvt<<<2048, 256, 0, stream>>>(x, xb, N_TOK*INDIM/4);
  k_tcvt<<<512, 256, 0, stream>>>(Wq, wqkt, INDIM, DMODEL);
  k_tcvt<<<512, 256, 0, stream>>>(Wk, wqkt + (size_t)DMODEL*INDIM, INDIM, DMODEL);
  k_tcvt<<<512, 256, 0, stream>>>(Wv, wvt, INDIM, DMODEL);
  k_tcvt<<<256, 256, 0, stream>>>(W1, w1t, DMODEL, DMODEL/2);
  k_bias2<<<4, 256, 0, stream>>>(bq, bk, bqk);

  // fused Q|K projection: [8192][1024]
  k_gemm<0,0,0><<<dim3(32, 8), 512, 0, stream>>>(xb, wqkt, bqk, qkb,
      N_TOK, 2*DMODEL, INDIM, INDIM, INDIM, 2*DMODEL, 0.f, nullptr, 0);
  // V^T split-K z=2 + combine
  k_gemm<3,0,0><<<dim3(2, 64, 2), 512, 0, stream>>>(wvt, xb, nullptr, vpp,
      DMODEL, N_TOK, INDIM/2, INDIM, INDIM, N_TOK, 0.f, nullptr, 0);
  k_vcomb<<<DMODEL*N_TOK/8/256, 256, 0, stream>>>(vpp, bv, vtb);

  const float scale = 0.04419417382415922f;  // 1/sqrt(512)
  const __bf16* Qm = qkb;            // lda 1024
  const __bf16* Km = qkb + DMODEL;   // ldb 1024
  // ---- half 0 ----
  k_gemm<2,1,1><<<1024, 512, 0, stream>>>(Qm, Km, nullptr, Ph,
      N_TOK, NHALF, DMODEL, 2*DMODEL, 2*DMODEL, NHALF, scale, rsp, 0);
  k_gemm<3,2,0><<<256, 512, 0, stream>>>(Ph, vtb, nullptr, p00,
      N_TOK, DMODEL, NHALF/2, NHALF, N_TOK, DMODEL, 0.f, nullptr, 0);
  // ---- half 1 ----
  k_gemm<2,1,1><<<1024, 512, 0, stream>>>(Qm, Km + (size_t)NHALF*2*DMODEL, nullptr, Ph,
      N_TOK, NHALF, DMODEL, 2*DMODEL, 2*DMODEL, NHALF, scale, rsp, 64);
  k_gemm<3,2,0><<<256, 512, 0, stream>>>(Ph, vtb + NHALF, nullptr, p10,
      N_TOK, DMODEL, NHALF/2, NHALF, N_TOK, DMODEL, 0.f, nullptr, 0);

  k_rsum<<<32, 256, 0, stream>>>(rsp, rs);
  k_mlp<<<N_TOK/64, 256, 0, stream>>>(p00, p01, p10, p11, rs,
      w1t, b1, W2, b2, out);

  (void)in_sizes; (void)n_in; (void)out_size; (void)ws_size;
}

// Round 19
// 272.001 us; speedup vs baseline: 1.1284x; 1.1284x over previous
//
#include <hip/hip_runtime.h>
#include <hip/hip_bf16.h>
#include <cstdint>
#include <cstddef>

typedef float  f32x4  __attribute__((ext_vector_type(4)));
typedef __bf16 bf16x8 __attribute__((ext_vector_type(8)));
typedef __bf16 bf16x4 __attribute__((ext_vector_type(4)));

#define N_TOK  8192
#define INDIM  1024
#define DMODEL 512
#define NHALF  4096   // key-split half for P materialization

__device__ __forceinline__ f32x4 mfma16x16x32(bf16x8 a, bf16x8 b, f32x4 c){
  return __builtin_amdgcn_mfma_f32_16x16x32_bf16(a, b, c, 0, 0, 0);
}

__device__ __forceinline__ void async_copy16(void* lds, const void* g){
  __builtin_amdgcn_global_load_lds((__attribute__((address_space(1))) void*)g,
                                   (__attribute__((address_space(3))) void*)lds,
                                   16, 0, 0);
}

// ---------------- convert / transpose / bias-concat ----------------
__global__ void k_cvt(const float* __restrict__ in, __bf16* __restrict__ out, int n4){
  int stride = gridDim.x * blockDim.x;
  for (int i = blockIdx.x * blockDim.x + threadIdx.x; i < n4; i += stride){
    f32x4 v = ((const f32x4*)in)[i];
    bf16x4 o;
    o[0]=(__bf16)v[0]; o[1]=(__bf16)v[1]; o[2]=(__bf16)v[2]; o[3]=(__bf16)v[3];
    ((bf16x4*)out)[i] = o;
  }
}

__global__ void k_tcvt(const float* __restrict__ W, __bf16* __restrict__ Wt, int Kd, int Nd){
  int total = Kd * Nd;
  int stride = gridDim.x * blockDim.x;
  for (int i = blockIdx.x * blockDim.x + threadIdx.x; i < total; i += stride){
    int k = i / Nd, n = i - k * Nd;
    Wt[(size_t)n * Kd + k] = (__bf16)W[i];
  }
}

__global__ void k_bias2(const float* __restrict__ a, const float* __restrict__ b,
                        float* __restrict__ o){
  int idx = blockIdx.x * 256 + threadIdx.x;   // 0..1023
  o[idx] = (idx < 512) ? a[idx] : b[idx - 512];
}

// ---------------- generalized GEMM: C[M,N] = A[M,K-chunk] @ Bt^T ------------
// 128x128 tile, BK=64, double-buffered, 2-phase (stage-next issued before
// compute, one __syncthreads/iter). LDS [128][64] with 16B-slot XOR swizzle
// (s ^= row&7): linear gload_lds dest + pre-swizzled global source +
// swizzled ds_read (rule-21 both-sides involution). 32 MFMA / sync pair.
// EPI: 0 = +bias[col]; 2 = exp(scale*acc); 3 = plain.
// MAP: 0 = (x=m, y=n, z=K-chunk); 1 = xcd-chunked m (grid 2048);
//      2 = z = xcd>>2, n innermost (grid 512).
// RSUM: fused per-(colblock,row) partial row sums from acc (deterministic).
template<int EPI, int MAP, int RSUM>
__global__ __launch_bounds__(256) void k_gemm(
    const __bf16* __restrict__ A, const __bf16* __restrict__ Bt,
    const float* __restrict__ bias, __bf16* __restrict__ C,
    int M, int N, int K, int lda, int ldb, int ldc, float scale,
    float* __restrict__ rsp, int rbase)
{
  __shared__ __bf16 Als[2][128*64];   // 32 KB
  __shared__ __bf16 Bls[2][128*64];   // 32 KB
  const int tid = threadIdx.x;
  const int w = tid >> 6, l = tid & 63;
  const int lr = l & 15, lg = l >> 4;
  const int wr = w >> 1, wc = w & 1;
  int m0, n0, kz, zsel;
  if (MAP == 0){
    m0 = blockIdx.x * 128; n0 = blockIdx.y * 128; zsel = blockIdx.z; kz = zsel * K;
  } else if (MAP == 1){
    int lin = blockIdx.x, xcd = lin & 7, idx = lin >> 3;
    m0 = (xcd*8 + (idx & 7)) * 128; n0 = (idx >> 3) * 128; zsel = 0; kz = 0;
  } else {
    int lin = blockIdx.x, xcd = lin & 7, i = lin >> 3;
    zsel = xcd >> 2; kz = zsel * K;
    m0 = ((xcd & 3)*16 + (i >> 2)) * 128; n0 = (i & 3) * 128;
  }
  // stage addressing: dest byte f = ro*4096 + w*1024 + l*16
  //   row = ro*32 + w*8 + (l>>3), slot = l&7; source col pre-swizzled:
  //   colelems = ((l&7) ^ (l>>3)) * 8   (row&7 == l>>3)
  const int srow = w*8 + (l >> 3);
  const int scol = ((l & 7) ^ (l >> 3)) * 8;

  auto stage = [&](int b, int kk){
    #pragma unroll
    for (int ro = 0; ro < 4; ++ro)
      async_copy16((char*)&Als[b][0] + ro*4096 + w*1024,
                   A  + (size_t)(m0 + ro*32 + srow) * lda + kk + scol);
    #pragma unroll
    for (int ro = 0; ro < 4; ++ro)
      async_copy16((char*)&Bls[b][0] + ro*4096 + w*1024,
                   Bt + (size_t)(n0 + ro*32 + srow) * ldb + kk + scol);
  };

  f32x4 acc[4][4] = {};
  const int nt = K >> 6;
  stage(0, kz);
  __syncthreads();
  const int r7 = lr & 7;
  for (int t = 0; t < nt; ++t){
    const int cur = t & 1;
    if (t + 1 < nt) stage(cur ^ 1, kz + (t+1)*64);   // issue-early
    #pragma unroll
    for (int kk = 0; kk < 2; ++kk){
      const int cs = ((kk*4 + lg) ^ r7) * 8;   // swizzled 16B slot
      bf16x8 af[4], bfv[4];
      #pragma unroll
      for (int mf = 0; mf < 4; ++mf)
        af[mf]  = *(const bf16x8*)&Als[cur][(wr*64 + mf*16 + lr)*64 + cs];
      #pragma unroll
      for (int nf = 0; nf < 4; ++nf)
        bfv[nf] = *(const bf16x8*)&Bls[cur][(wc*64 + nf*16 + lr)*64 + cs];
      #pragma unroll
      for (int mf = 0; mf < 4; ++mf)
        #pragma unroll
        for (int nf = 0; nf < 4; ++nf)
          acc[mf][nf] = mfma16x16x32(af[mf], bfv[nf], acc[mf][nf]);
    }
    __syncthreads();   // drains stage (issued a full phase earlier) + reads
  }
  // ---- epilogue: direct scattered stores + optional fused row sums ----
  __bf16* Cd = C + (size_t)zsel * (size_t)M * ldc;
  float rsp4[4][4];
  #pragma unroll
  for (int mf = 0; mf < 4; ++mf)
    #pragma unroll
    for (int r = 0; r < 4; ++r) rsp4[mf][r] = 0.0f;
  #pragma unroll
  for (int mf = 0; mf < 4; ++mf)
    #pragma unroll
    for (int nf = 0; nf < 4; ++nf)
      #pragma unroll
      for (int r = 0; r < 4; ++r){
        int row = m0 + wr*64 + mf*16 + lg*4 + r;
        int col = n0 + wc*64 + nf*16 + lr;
        float v = acc[mf][nf][r];
        if (EPI == 0) v += bias[col];
        if (EPI == 2) v = __expf(v * scale);
        Cd[(size_t)row * ldc + col] = (__bf16)v;
        if (RSUM) rsp4[mf][r] += v;
      }
  if (RSUM){
    #pragma unroll
    for (int mf = 0; mf < 4; ++mf)
      #pragma unroll
      for (int r = 0; r < 4; ++r)
        #pragma unroll
        for (int dl = 1; dl < 16; dl <<= 1)
          rsp4[mf][r] += __shfl_xor(rsp4[mf][r], dl);
    if (lr == 0){
      int cb = rbase + (n0 >> 6) + wc;
      #pragma unroll
      for (int mf = 0; mf < 4; ++mf)
        #pragma unroll
        for (int r = 0; r < 4; ++r)
          rsp[(size_t)cb * N_TOK + m0 + wr*64 + mf*16 + lg*4 + r] = rsp4[mf][r];
    }
  }
}

// ---------------- rs[row] = sum of 128 rsp partials ----------------
__global__ __launch_bounds__(256) void k_rsum(
    const float* __restrict__ rsp, float* __restrict__ rs)
{
  int row = blockIdx.x * 256 + threadIdx.x;   // 8192
  float s = 0.0f;
  #pragma unroll 8
  for (int j = 0; j < 128; ++j) s += rsp[(size_t)j * N_TOK + row];
  rs[row] = s;
}

// ---------------- V-projection split-K combine: vtb = p0 + p1 + bv[row] -----
__global__ __launch_bounds__(256) void k_vcomb(
    const __bf16* __restrict__ p, const float* __restrict__ bv,
    __bf16* __restrict__ vtb)
{
  int idx = blockIdx.x * 256 + threadIdx.x;   // 512*8192/8
  int row = idx >> 10;
  float b = bv[row];
  bf16x8 a = ((const bf16x8*)p)[idx];
  bf16x8 c = ((const bf16x8*)(p + (size_t)DMODEL * N_TOK))[idx];
  bf16x8 o;
  #pragma unroll
  for (int i = 0; i < 8; ++i)
    o[i] = (__bf16)((float)a[i] + (float)c[i] + b);
  ((bf16x8*)vtb)[idx] = o;
}

// ---------------- MLP head (fused 4-partial combine + GEMM + reduce) --------
__global__ __launch_bounds__(256) void k_mlp(
    const __bf16* __restrict__ p00, const __bf16* __restrict__ p01,
    const __bf16* __restrict__ p10, const __bf16* __restrict__ p11,
    const float* __restrict__ rs, const __bf16* __restrict__ W1t,
    const float* __restrict__ b1, const float* __restrict__ W2,
    const float* __restrict__ b2, float* __restrict__ out)
{
  __shared__ __bf16 Als[64][512];
  __shared__ float  red[4][64];
  const int tid = threadIdx.x;
  const int w = tid >> 6, l = tid & 63;
  const int lr = l & 15, lg = l >> 4;
  const int m0 = blockIdx.x * 64;
  #pragma unroll
  for (int i = 0; i < 16; ++i){
    int chunk = i*256 + tid;            // 0..4095
    int rl = chunk >> 6, c8 = chunk & 63;
    size_t off = (size_t)(m0 + rl) * 64 + c8;
    float inv = 1.0f / rs[m0 + rl];
    bf16x8 a = ((const bf16x8*)p00)[off];
    bf16x8 b = ((const bf16x8*)p01)[off];
    bf16x8 c = ((const bf16x8*)p10)[off];
    bf16x8 d = ((const bf16x8*)p11)[off];
    bf16x8 o;
    #pragma unroll
    for (int j = 0; j < 8; ++j)
      o[j] = (__bf16)((((float)a[j] + (float)b[j]) + ((float)c[j] + (float)d[j])) * inv);
    *(bf16x8*)&Als[rl][c8*8] = o;
  }
  __syncthreads();
  f32x4 acc[4][4] = {};
  for (int t = 0; t < 16; ++t){
    bf16x8 af[4];
    #pragma unroll
    for (int mf2 = 0; mf2 < 4; ++mf2) af[mf2] = *(const bf16x8*)&Als[mf2*16 + lr][t*32 + lg*8];
    #pragma unroll
    for (int nf2 = 0; nf2 < 4; ++nf2){
      bf16x8 bfr = *(const bf16x8*)&W1t[(size_t)(w*64 + nf2*16 + lr)*DMODEL + t*32 + lg*8];
      #pragma unroll
      for (int mf2 = 0; mf2 < 4; ++mf2)
        acc[mf2][nf2] = mfma16x16x32(af[mf2], bfr, acc[mf2][nf2]);
    }
  }
  float part[4][4] = {};
  #pragma unroll
  for (int nf2 = 0; nf2 < 4; ++nf2){
    int col = w*64 + nf2*16 + lr;
    float bb = b1[col], w2v = W2[col];
    #pragma unroll
    for (int mf2 = 0; mf2 < 4; ++mf2)
      #pragma unroll
      for (int r = 0; r < 4; ++r){
        float h = acc[mf2][nf2][r] + bb;
        h = h > 0.0f ? h : 0.0f;
        part[mf2][r] += h * w2v;
      }
  }
  #pragma unroll
  for (int mf2 = 0; mf2 < 4; ++mf2)
    #pragma unroll
    for (int r = 0; r < 4; ++r)
      #pragma unroll
      for (int dl = 1; dl < 16; dl <<= 1)
        part[mf2][r] += __shfl_xor(part[mf2][r], dl);
  if (lr == 0){
    #pragma unroll
    for (int mf2 = 0; mf2 < 4; ++mf2)
      #pragma unroll
      for (int r = 0; r < 4; ++r)
        red[w][mf2*16 + lg*4 + r] = part[mf2][r];
  }
  __syncthreads();
  if (tid < 64)
    out[m0 + tid] = red[0][tid] + red[1][tid] + red[2][tid] + red[3][tid] + b2[0];
}

// ---------------- launcher ----------------
extern "C" void kernel_launch(void* const* d_in, const int* in_sizes, int n_in,
                              void* d_out, int out_size, void* d_ws, size_t ws_size,
                              hipStream_t stream)
{
  const float* x  = (const float*)d_in[0];
  const float* Wq = (const float*)d_in[1];
  const float* bq = (const float*)d_in[2];
  const float* Wk = (const float*)d_in[3];
  const float* bk = (const float*)d_in[4];
  const float* Wv = (const float*)d_in[5];
  const float* bv = (const float*)d_in[6];
  const float* W1 = (const float*)d_in[7];
  const float* b1 = (const float*)d_in[8];
  const float* W2 = (const float*)d_in[9];
  const float* b2 = (const float*)d_in[10];
  float* out = (float*)d_out;
  char* ws = (char*)d_ws;
  // workspace layout
  __bf16* xb   = (__bf16*)(ws + 0);          // 16 MB (dead after V GEMM)
  __bf16* qkb  = (__bf16*)(ws + 16777216);   // 16 MB [8192][1024] rows [q|k]
  __bf16* vtb  = (__bf16*)(ws + 33554432);   // 8 MB  V^T [512][8192]
  __bf16* wqkt = (__bf16*)(ws + 50331648);   // 2 MB  [Wq^T ; Wk^T]
  __bf16* wvt  = (__bf16*)(ws + 52428800);   // 1 MB
  __bf16* w1t  = (__bf16*)(ws + 53477376);   // 0.25 MB -> ends 53739520
  float*  rs   = (float*)(ws + 53739520);    // 32 KB
  float*  bqk  = (float*)(ws + 53772288);    // 4 KB
  float*  rsp  = (float*)(ws + 54525952);    // 4 MB  [128][8192] partial row sums
  __bf16* Ph   = (__bf16*)(ws + 58720256);   // 64 MB  P half [8192][4096]
  __bf16* vpp  = (__bf16*)(ws + 58720256);   // V-proj partials (Ph region, early)
  // PV split-K partials (dead-region reuse)
  __bf16* p00  = (__bf16*)(ws + 0);          // xb region
  __bf16* p01  = (__bf16*)(ws + 8388608);
  __bf16* p10  = (__bf16*)(ws + 16777216);   // qkb region (dead after pexp1)
  __bf16* p11  = (__bf16*)(ws + 25165824);

  k_cvt<<<2048, 256, 0, stream>>>(x, xb, N_TOK*INDIM/4);
  k_tcvt<<<512, 256, 0, stream>>>(Wq, wqkt, INDIM, DMODEL);
  k_tcvt<<<512, 256, 0, stream>>>(Wk, wqkt + (size_t)DMODEL*INDIM, INDIM, DMODEL);
  k_tcvt<<<512, 256, 0, stream>>>(Wv, wvt, INDIM, DMODEL);
  k_tcvt<<<256, 256, 0, stream>>>(W1, w1t, DMODEL, DMODEL/2);
  k_bias2<<<4, 256, 0, stream>>>(bq, bk, bqk);

  // fused Q|K projection
  k_gemm<0,0,0><<<dim3(64, 8), 256, 0, stream>>>(xb, wqkt, bqk, qkb,
      N_TOK, 2*DMODEL, INDIM, INDIM, INDIM, 2*DMODEL, 0.f, nullptr, 0);
  // V^T split-K + combine
  k_gemm<3,0,0><<<dim3(4, 64, 2), 256, 0, stream>>>(wvt, xb, nullptr, vpp,
      DMODEL, N_TOK, INDIM/2, INDIM, INDIM, N_TOK, 0.f, nullptr, 0);
  k_vcomb<<<DMODEL*N_TOK/8/256, 256, 0, stream>>>(vpp, bv, vtb);

  const float scale = 0.04419417382415922f;  // 1/sqrt(512)
  const __bf16* Qm = qkb;            // lda 1024
  const __bf16* Km = qkb + DMODEL;   // ldb 1024
  // ---- half 0 ----
  k_gemm<2,1,1><<<2048, 256, 0, stream>>>(Qm, Km, nullptr, Ph,
      N_TOK, NHALF, DMODEL, 2*DMODEL, 2*DMODEL, NHALF, scale, rsp, 0);
  k_gemm<3,2,0><<<512, 256, 0, stream>>>(Ph, vtb, nullptr, p00,
      N_TOK, DMODEL, NHALF/2, NHALF, N_TOK, DMODEL, 0.f, nullptr, 0);
  // ---- half 1 ----
  k_gemm<2,1,1><<<2048, 256, 0, stream>>>(Qm, Km + (size_t)NHALF*2*DMODEL, nullptr, Ph,
      N_TOK, NHALF, DMODEL, 2*DMODEL, 2*DMODEL, NHALF, scale, rsp, 64);
  k_gemm<3,2,0><<<512, 256, 0, stream>>>(Ph, vtb + NHALF, nullptr, p10,
      N_TOK, DMODEL, NHALF/2, NHALF, N_TOK, DMODEL, 0.f, nullptr, 0);

  k_rsum<<<32, 256, 0, stream>>>(rsp, rs);
  k_mlp<<<N_TOK/64, 256, 0, stream>>>(p00, p01, p10, p11, rs,
      w1t, b1, W2, b2, out);

  (void)in_sizes; (void)n_in; (void)out_size; (void)ws_size;
}

// Round 20
// 265.059 us; speedup vs baseline: 1.1580x; 1.0262x over previous
//
#include <hip/hip_runtime.h>
#include <hip/hip_bf16.h>
#include <cstdint>
#include <cstddef>

typedef float  f32x4  __attribute__((ext_vector_type(4)));
typedef __bf16 bf16x8 __attribute__((ext_vector_type(8)));
typedef __bf16 bf16x4 __attribute__((ext_vector_type(4)));

#define N_TOK  8192
#define INDIM  1024
#define DMODEL 512
#define NHALF  4096   // key-split half for P materialization

__device__ __forceinline__ f32x4 mfma16x16x32(bf16x8 a, bf16x8 b, f32x4 c){
  return __builtin_amdgcn_mfma_f32_16x16x32_bf16(a, b, c, 0, 0, 0);
}

__device__ __forceinline__ void async_copy16(void* lds, const void* g){
  __builtin_amdgcn_global_load_lds((__attribute__((address_space(1))) void*)g,
                                   (__attribute__((address_space(3))) void*)lds,
                                   16, 0, 0);
}

// ---------------- x -> bf16 ----------------
__global__ void k_cvt(const float* __restrict__ in, __bf16* __restrict__ out, int n4){
  int stride = gridDim.x * blockDim.x;
  for (int i = blockIdx.x * blockDim.x + threadIdx.x; i < n4; i += stride){
    f32x4 v = ((const f32x4*)in)[i];
    bf16x4 o;
    o[0]=(__bf16)v[0]; o[1]=(__bf16)v[1]; o[2]=(__bf16)v[2]; o[3]=(__bf16)v[3];
    ((bf16x4*)out)[i] = o;
  }
}

// ---------------- fused prep: 4 weight transposes + bias concat ----------------
__global__ void k_prep(const float* __restrict__ Wq, const float* __restrict__ Wk,
                       const float* __restrict__ Wv, const float* __restrict__ W1,
                       const float* __restrict__ bq, const float* __restrict__ bk,
                       __bf16* __restrict__ wqkt, __bf16* __restrict__ wvt,
                       __bf16* __restrict__ w1t, float* __restrict__ bqk)
{
  const int WQK = INDIM * DMODEL;              // 524288
  const int W1N = DMODEL * (DMODEL/2);         // 131072
  const int TOT = 3*WQK + W1N + 2*DMODEL;
  int stride = gridDim.x * blockDim.x;
  for (int i = blockIdx.x * blockDim.x + threadIdx.x; i < TOT; i += stride){
    if (i < WQK){
      int k = i / DMODEL, n = i - k*DMODEL;
      wqkt[(size_t)n * INDIM + k] = (__bf16)Wq[i];
    } else if (i < 2*WQK){
      int j = i - WQK; int k = j / DMODEL, n = j - k*DMODEL;
      wqkt[(size_t)(DMODEL + n) * INDIM + k] = (__bf16)Wk[j];
    } else if (i < 3*WQK){
      int j = i - 2*WQK; int k = j / DMODEL, n = j - k*DMODEL;
      wvt[(size_t)n * INDIM + k] = (__bf16)Wv[j];
    } else if (i < 3*WQK + W1N){
      int j = i - 3*WQK; int k = j / (DMODEL/2), n = j - k*(DMODEL/2);
      w1t[(size_t)n * DMODEL + k] = (__bf16)W1[j];
    } else {
      int j = i - 3*WQK - W1N;
      bqk[j] = (j < DMODEL) ? bq[j] : bk[j - DMODEL];
    }
  }
}

// ---------------- generalized GEMM: C[M,N] = A[M,K-chunk] @ Bt^T ------------
// 128x128 tile, BK=64, double-buffered, 2-phase (stage-next issued before
// compute, one __syncthreads/iter). LDS [128][64] with 16B-slot XOR swizzle
// (s ^= row&7): linear gload_lds dest + pre-swizzled global source +
// swizzled ds_read (rule-21 both-sides involution). 32 MFMA / sync pair.
// EPI: 0 = +bias[col]; 2 = exp(scale*acc); 3 = plain.
// MAP: 0 = (x=m, y=n, z=K-chunk); 1 = xcd-chunked m (grid 2048);
//      2 = z = xcd>>2, n innermost (grid 512).
// RSUM: fused per-(colblock,row) partial row sums from acc (deterministic).
template<int EPI, int MAP, int RSUM>
__global__ __launch_bounds__(256) void k_gemm(
    const __bf16* __restrict__ A, const __bf16* __restrict__ Bt,
    const float* __restrict__ bias, __bf16* __restrict__ C,
    int M, int N, int K, int lda, int ldb, int ldc, float scale,
    float* __restrict__ rsp, int rbase)
{
  __shared__ __bf16 Als[2][128*64];   // 32 KB
  __shared__ __bf16 Bls[2][128*64];   // 32 KB
  const int tid = threadIdx.x;
  const int w = tid >> 6, l = tid & 63;
  const int lr = l & 15, lg = l >> 4;
  const int wr = w >> 1, wc = w & 1;
  int m0, n0, kz, zsel;
  if (MAP == 0){
    m0 = blockIdx.x * 128; n0 = blockIdx.y * 128; zsel = blockIdx.z; kz = zsel * K;
  } else if (MAP == 1){
    int lin = blockIdx.x, xcd = lin & 7, idx = lin >> 3;
    m0 = (xcd*8 + (idx & 7)) * 128; n0 = (idx >> 3) * 128; zsel = 0; kz = 0;
  } else {
    int lin = blockIdx.x, xcd = lin & 7, i = lin >> 3;
    zsel = xcd >> 2; kz = zsel * K;
    m0 = ((xcd & 3)*16 + (i >> 2)) * 128; n0 = (i & 3) * 128;
  }
  const int srow = w*8 + (l >> 3);
  const int scol = ((l & 7) ^ (l >> 3)) * 8;

  auto stage = [&](int b, int kk){
    #pragma unroll
    for (int ro = 0; ro < 4; ++ro)
      async_copy16((char*)&Als[b][0] + ro*4096 + w*1024,
                   A  + (size_t)(m0 + ro*32 + srow) * lda + kk + scol);
    #pragma unroll
    for (int ro = 0; ro < 4; ++ro)
      async_copy16((char*)&Bls[b][0] + ro*4096 + w*1024,
                   Bt + (size_t)(n0 + ro*32 + srow) * ldb + kk + scol);
  };

  f32x4 acc[4][4] = {};
  const int nt = K >> 6;
  stage(0, kz);
  __syncthreads();
  const int r7 = lr & 7;
  for (int t = 0; t < nt; ++t){
    const int cur = t & 1;
    if (t + 1 < nt) stage(cur ^ 1, kz + (t+1)*64);   // issue-early
    #pragma unroll
    for (int kk = 0; kk < 2; ++kk){
      const int cs = ((kk*4 + lg) ^ r7) * 8;   // swizzled 16B slot
      bf16x8 af[4], bfv[4];
      #pragma unroll
      for (int mf = 0; mf < 4; ++mf)
        af[mf]  = *(const bf16x8*)&Als[cur][(wr*64 + mf*16 + lr)*64 + cs];
      #pragma unroll
      for (int nf = 0; nf < 4; ++nf)
        bfv[nf] = *(const bf16x8*)&Bls[cur][(wc*64 + nf*16 + lr)*64 + cs];
      #pragma unroll
      for (int mf = 0; mf < 4; ++mf)
        #pragma unroll
        for (int nf = 0; nf < 4; ++nf)
          acc[mf][nf] = mfma16x16x32(af[mf], bfv[nf], acc[mf][nf]);
    }
    __syncthreads();   // drains stage (issued a full phase earlier) + reads
  }
  // ---- epilogue: direct scattered stores + optional fused row sums ----
  __bf16* Cd = C + (size_t)zsel * (size_t)M * ldc;
  float rsp4[4][4];
  #pragma unroll
  for (int mf = 0; mf < 4; ++mf)
    #pragma unroll
    for (int r = 0; r < 4; ++r) rsp4[mf][r] = 0.0f;
  #pragma unroll
  for (int mf = 0; mf < 4; ++mf)
    #pragma unroll
    for (int nf = 0; nf < 4; ++nf)
      #pragma unroll
      for (int r = 0; r < 4; ++r){
        int row = m0 + wr*64 + mf*16 + lg*4 + r;
        int col = n0 + wc*64 + nf*16 + lr;
        float v = acc[mf][nf][r];
        if (EPI == 0) v += bias[col];
        if (EPI == 2) v = __expf(v * scale);
        Cd[(size_t)row * ldc + col] = (__bf16)v;
        if (RSUM) rsp4[mf][r] += v;
      }
  if (RSUM){
    #pragma unroll
    for (int mf = 0; mf < 4; ++mf)
      #pragma unroll
      for (int r = 0; r < 4; ++r)
        #pragma unroll
        for (int dl = 1; dl < 16; dl <<= 1)
          rsp4[mf][r] += __shfl_xor(rsp4[mf][r], dl);
    if (lr == 0){
      int cb = rbase + (n0 >> 6) + wc;
      #pragma unroll
      for (int mf = 0; mf < 4; ++mf)
        #pragma unroll
        for (int r = 0; r < 4; ++r)
          rsp[(size_t)cb * N_TOK + m0 + wr*64 + mf*16 + lg*4 + r] = rsp4[mf][r];
    }
  }
}

// ---------------- V-projection split-K combine: vtb = p0 + p1 + bv[row] -----
__global__ __launch_bounds__(256) void k_vcomb(
    const __bf16* __restrict__ p, const float* __restrict__ bv,
    __bf16* __restrict__ vtb)
{
  int idx = blockIdx.x * 256 + threadIdx.x;   // 512*8192/8
  int row = idx >> 10;
  float b = bv[row];
  bf16x8 a = ((const bf16x8*)p)[idx];
  bf16x8 c = ((const bf16x8*)(p + (size_t)DMODEL * N_TOK))[idx];
  bf16x8 o;
  #pragma unroll
  for (int i = 0; i < 8; ++i)
    o[i] = (__bf16)((float)a[i] + (float)c[i] + b);
  ((bf16x8*)vtb)[idx] = o;
}

// ---------------- MLP head (fused rs-reduce + 4-partial combine + GEMM) -----
__global__ __launch_bounds__(256) void k_mlp(
    const __bf16* __restrict__ p00, const __bf16* __restrict__ p01,
    const __bf16* __restrict__ p10, const __bf16* __restrict__ p11,
    const float* __restrict__ rsp, const __bf16* __restrict__ W1t,
    const float* __restrict__ b1, const float* __restrict__ W2,
    const float* __restrict__ b2, float* __restrict__ out)
{
  __shared__ __bf16 Als[64][512];
  __shared__ float  red[4][64];
  __shared__ float  rsv[64];
  const int tid = threadIdx.x;
  const int w = tid >> 6, l = tid & 63;
  const int lr = l & 15, lg = l >> 4;
  const int m0 = blockIdx.x * 64;
  // rs for this block's 64 rows (same serial order as the old k_rsum)
  if (tid < 64){
    float s = 0.0f;
    #pragma unroll 8
    for (int j = 0; j < 128; ++j) s += rsp[(size_t)j * N_TOK + m0 + tid];
    rsv[tid] = s;
  }
  __syncthreads();
  #pragma unroll
  for (int i = 0; i < 16; ++i){
    int chunk = i*256 + tid;            // 0..4095
    int rl = chunk >> 6, c8 = chunk & 63;
    size_t off = (size_t)(m0 + rl) * 64 + c8;
    float inv = 1.0f / rsv[rl];
    bf16x8 a = ((const bf16x8*)p00)[off];
    bf16x8 b = ((const bf16x8*)p01)[off];
    bf16x8 c = ((const bf16x8*)p10)[off];
    bf16x8 d = ((const bf16x8*)p11)[off];
    bf16x8 o;
    #pragma unroll
    for (int j = 0; j < 8; ++j)
      o[j] = (__bf16)((((float)a[j] + (float)b[j]) + ((float)c[j] + (float)d[j])) * inv);
    *(bf16x8*)&Als[rl][c8*8] = o;
  }
  __syncthreads();
  f32x4 acc[4][4] = {};
  for (int t = 0; t < 16; ++t){
    bf16x8 af[4];
    #pragma unroll
    for (int mf2 = 0; mf2 < 4; ++mf2) af[mf2] = *(const bf16x8*)&Als[mf2*16 + lr][t*32 + lg*8];
    #pragma unroll
    for (int nf2 = 0; nf2 < 4; ++nf2){
      bf16x8 bfr = *(const bf16x8*)&W1t[(size_t)(w*64 + nf2*16 + lr)*DMODEL + t*32 + lg*8];
      #pragma unroll
      for (int mf2 = 0; mf2 < 4; ++mf2)
        acc[mf2][nf2] = mfma16x16x32(af[mf2], bfr, acc[mf2][nf2]);
    }
  }
  float part[4][4] = {};
  #pragma unroll
  for (int nf2 = 0; nf2 < 4; ++nf2){
    int col = w*64 + nf2*16 + lr;
    float bb = b1[col], w2v = W2[col];
    #pragma unroll
    for (int mf2 = 0; mf2 < 4; ++mf2)
      #pragma unroll
      for (int r = 0; r < 4; ++r){
        float h = acc[mf2][nf2][r] + bb;
        h = h > 0.0f ? h : 0.0f;
        part[mf2][r] += h * w2v;
      }
  }
  #pragma unroll
  for (int mf2 = 0; mf2 < 4; ++mf2)
    #pragma unroll
    for (int r = 0; r < 4; ++r)
      #pragma unroll
      for (int dl = 1; dl < 16; dl <<= 1)
        part[mf2][r] += __shfl_xor(part[mf2][r], dl);
  if (lr == 0){
    #pragma unroll
    for (int mf2 = 0; mf2 < 4; ++mf2)
      #pragma unroll
      for (int r = 0; r < 4; ++r)
        red[w][mf2*16 + lg*4 + r] = part[mf2][r];
  }
  __syncthreads();
  if (tid < 64)
    out[m0 + tid] = red[0][tid] + red[1][tid] + red[2][tid] + red[3][tid] + b2[0];
}

// ---------------- launcher ----------------
extern "C" void kernel_launch(void* const* d_in, const int* in_sizes, int n_in,
                              void* d_out, int out_size, void* d_ws, size_t ws_size,
                              hipStream_t stream)
{
  const float* x  = (const float*)d_in[0];
  const float* Wq = (const float*)d_in[1];
  const float* bq = (const float*)d_in[2];
  const float* Wk = (const float*)d_in[3];
  const float* bk = (const float*)d_in[4];
  const float* Wv = (const float*)d_in[5];
  const float* bv = (const float*)d_in[6];
  const float* W1 = (const float*)d_in[7];
  const float* b1 = (const float*)d_in[8];
  const float* W2 = (const float*)d_in[9];
  const float* b2 = (const float*)d_in[10];
  float* out = (float*)d_out;
  char* ws = (char*)d_ws;
  // workspace layout
  __bf16* xb   = (__bf16*)(ws + 0);          // 16 MB (dead after V GEMM)
  __bf16* qkb  = (__bf16*)(ws + 16777216);   // 16 MB [8192][1024] rows [q|k]
  __bf16* vtb  = (__bf16*)(ws + 33554432);   // 8 MB  V^T [512][8192]
  __bf16* wqkt = (__bf16*)(ws + 50331648);   // 2 MB  [Wq^T ; Wk^T]
  __bf16* wvt  = (__bf16*)(ws + 52428800);   // 1 MB
  __bf16* w1t  = (__bf16*)(ws + 53477376);   // 0.25 MB -> ends 53739520
  float*  bqk  = (float*)(ws + 53772288);    // 4 KB
  float*  rsp  = (float*)(ws + 54525952);    // 4 MB  [128][8192] partial row sums
  __bf16* Ph   = (__bf16*)(ws + 58720256);   // 64 MB  P half [8192][4096]
  __bf16* vpp  = (__bf16*)(ws + 58720256);   // V-proj partials (Ph region, early)
  // PV split-K partials (dead-region reuse)
  __bf16* p00  = (__bf16*)(ws + 0);          // xb region
  __bf16* p01  = (__bf16*)(ws + 8388608);
  __bf16* p10  = (__bf16*)(ws + 16777216);   // qkb region (dead after pexp1)
  __bf16* p11  = (__bf16*)(ws + 25165824);

  k_cvt<<<2048, 256, 0, stream>>>(x, xb, N_TOK*INDIM/4);
  k_prep<<<1024, 256, 0, stream>>>(Wq, Wk, Wv, W1, bq, bk, wqkt, wvt, w1t, bqk);

  // fused Q|K projection
  k_gemm<0,0,0><<<dim3(64, 8), 256, 0, stream>>>(xb, wqkt, bqk, qkb,
      N_TOK, 2*DMODEL, INDIM, INDIM, INDIM, 2*DMODEL, 0.f, nullptr, 0);
  // V^T split-K + combine
  k_gemm<3,0,0><<<dim3(4, 64, 2), 256, 0, stream>>>(wvt, xb, nullptr, vpp,
      DMODEL, N_TOK, INDIM/2, INDIM, INDIM, N_TOK, 0.f, nullptr, 0);
  k_vcomb<<<DMODEL*N_TOK/8/256, 256, 0, stream>>>(vpp, bv, vtb);

  const float scale = 0.04419417382415922f;  // 1/sqrt(512)
  const __bf16* Qm = qkb;            // lda 1024
  const __bf16* Km = qkb + DMODEL;   // ldb 1024
  // ---- half 0 ----
  k_gemm<2,1,1><<<2048, 256, 0, stream>>>(Qm, Km, nullptr, Ph,
      N_TOK, NHALF, DMODEL, 2*DMODEL, 2*DMODEL, NHALF, scale, rsp, 0);
  k_gemm<3,2,0><<<512, 256, 0, stream>>>(Ph, vtb, nullptr, p00,
      N_TOK, DMODEL, NHALF/2, NHALF, N_TOK, DMODEL, 0.f, nullptr, 0);
  // ---- half 1 ----
  k_gemm<2,1,1><<<2048, 256, 0, stream>>>(Qm, Km + (size_t)NHALF*2*DMODEL, nullptr, Ph,
      N_TOK, NHALF, DMODEL, 2*DMODEL, 2*DMODEL, NHALF, scale, rsp, 64);
  k_gemm<3,2,0><<<512, 256, 0, stream>>>(Ph, vtb + NHALF, nullptr, p10,
      N_TOK, DMODEL, NHALF/2, NHALF, N_TOK, DMODEL, 0.f, nullptr, 0);

  k_mlp<<<N_TOK/64, 256, 0, stream>>>(p00, p01, p10, p11, rsp,
      w1t, b1, W2, b2, out);

  (void)in_sizes; (void)n_in; (void)out_size; (void)ws_size;
}

// Round 21
// 255.212 us; speedup vs baseline: 1.2027x; 1.0386x over previous
//
#include <hip/hip_runtime.h>
#include <hip/hip_bf16.h>
#include <cstdint>
#include <cstddef>

typedef float  f32x4  __attribute__((ext_vector_type(4)));
typedef __bf16 bf16x8 __attribute__((ext_vector_type(8)));
typedef __bf16 bf16x4 __attribute__((ext_vector_type(4)));

#define N_TOK  8192
#define INDIM  1024
#define DMODEL 512
#define NHALF  4096   // key-split half for P materialization

__device__ __forceinline__ f32x4 mfma16x16x32(bf16x8 a, bf16x8 b, f32x4 c){
  return __builtin_amdgcn_mfma_f32_16x16x32_bf16(a, b, c, 0, 0, 0);
}

__device__ __forceinline__ void async_copy16(void* lds, const void* g){
  __builtin_amdgcn_global_load_lds((__attribute__((address_space(1))) void*)g,
                                   (__attribute__((address_space(3))) void*)lds,
                                   16, 0, 0);
}

// ---------------- x -> bf16 ----------------
__global__ void k_cvt(const float* __restrict__ in, __bf16* __restrict__ out, int n4){
  int stride = gridDim.x * blockDim.x;
  for (int i = blockIdx.x * blockDim.x + threadIdx.x; i < n4; i += stride){
    f32x4 v = ((const f32x4*)in)[i];
    bf16x4 o;
    o[0]=(__bf16)v[0]; o[1]=(__bf16)v[1]; o[2]=(__bf16)v[2]; o[3]=(__bf16)v[3];
    ((bf16x4*)out)[i] = o;
  }
}

// ---------------- fused prep: 4 weight transposes + bias concat ----------------
__global__ void k_prep(const float* __restrict__ Wq, const float* __restrict__ Wk,
                       const float* __restrict__ Wv, const float* __restrict__ W1,
                       const float* __restrict__ bq, const float* __restrict__ bk,
                       __bf16* __restrict__ wqkt, __bf16* __restrict__ wvt,
                       __bf16* __restrict__ w1t, float* __restrict__ bqk)
{
  const int WQK = INDIM * DMODEL;              // 524288
  const int W1N = DMODEL * (DMODEL/2);         // 131072
  const int TOT = 3*WQK + W1N + 2*DMODEL;
  int stride = gridDim.x * blockDim.x;
  for (int i = blockIdx.x * blockDim.x + threadIdx.x; i < TOT; i += stride){
    if (i < WQK){
      int k = i / DMODEL, n = i - k*DMODEL;
      wqkt[(size_t)n * INDIM + k] = (__bf16)Wq[i];
    } else if (i < 2*WQK){
      int j = i - WQK; int k = j / DMODEL, n = j - k*DMODEL;
      wqkt[(size_t)(DMODEL + n) * INDIM + k] = (__bf16)Wk[j];
    } else if (i < 3*WQK){
      int j = i - 2*WQK; int k = j / DMODEL, n = j - k*DMODEL;
      wvt[(size_t)n * INDIM + k] = (__bf16)Wv[j];
    } else if (i < 3*WQK + W1N){
      int j = i - 3*WQK; int k = j / (DMODEL/2), n = j - k*(DMODEL/2);
      w1t[(size_t)n * DMODEL + k] = (__bf16)W1[j];
    } else {
      int j = i - 3*WQK - W1N;
      bqk[j] = (j < DMODEL) ? bq[j] : bk[j - DMODEL];
    }
  }
}

// ---------------- generalized GEMM: C[M,N] = A[M,K-chunk] @ Bt^T ------------
// 128x128 tile, BK=64, double-buffered 2-phase, swizzled LDS (R17-verified).
// MT: persistent m-tiles per block -- the last K-iter of tile mt stages tile
// (mt+1)'s first slab, so the pipeline never drains across m-tiles (amortizes
// the ~6-iter per-block fixed cost that dominates short-K shapes).
// EPI: 0 = +bias[col]; 2 = exp(scale*acc); 3 = plain.
// MAP: 0 = (x=m-group, y=n, z=K-chunk); 1 = xcd-chunked m-groups (pexp, MT=4,
//      grid 512); 2 = z = xcd>>2, n innermost (PV, grid 512).
// RSUM: fused per-(colblock,row) partial row sums from acc (deterministic).
template<int EPI, int MAP, int RSUM, int MT>
__global__ __launch_bounds__(256) void k_gemm(
    const __bf16* __restrict__ A, const __bf16* __restrict__ Bt,
    const float* __restrict__ bias, __bf16* __restrict__ C,
    int M, int N, int K, int lda, int ldb, int ldc, float scale,
    float* __restrict__ rsp, int rbase)
{
  __shared__ __bf16 Als[2][128*64];   // 32 KB
  __shared__ __bf16 Bls[2][128*64];   // 32 KB
  const int tid = threadIdx.x;
  const int w = tid >> 6, l = tid & 63;
  const int lr = l & 15, lg = l >> 4;
  const int wr = w >> 1, wc = w & 1;
  int blockm, n0, kz, zsel;
  if (MAP == 0){
    blockm = blockIdx.x; n0 = blockIdx.y * 128; zsel = blockIdx.z; kz = zsel * K;
  } else if (MAP == 1){
    // grid 512 (MT=4): xcd owns 2 m-groups (1024 rows, L2-resident); n inner
    int lin = blockIdx.x, xcd = lin & 7, idx = lin >> 3;   // idx 0..63
    blockm = xcd*2 + (idx & 1); n0 = (idx >> 1) * 128; zsel = 0; kz = 0;
  } else {
    // grid 512 (MT=1): z = xcd>>2 (L2-resident B z-slice), n innermost
    int lin = blockIdx.x, xcd = lin & 7, i = lin >> 3;
    zsel = xcd >> 2; kz = zsel * K;
    blockm = (xcd & 3)*16 + (i >> 2); n0 = (i & 3) * 128;
  }
  const int mbase = blockm * (128 * MT);
  const int srow = w*8 + (l >> 3);
  const int scol = ((l & 7) ^ (l >> 3)) * 8;

  auto stage = [&](int b, int moff, int kk){
    #pragma unroll
    for (int ro = 0; ro < 4; ++ro)
      async_copy16((char*)&Als[b][0] + ro*4096 + w*1024,
                   A  + (size_t)(mbase + moff + ro*32 + srow) * lda + kk + scol);
    #pragma unroll
    for (int ro = 0; ro < 4; ++ro)
      async_copy16((char*)&Bls[b][0] + ro*4096 + w*1024,
                   Bt + (size_t)(n0 + ro*32 + srow) * ldb + kk + scol);
  };

  const int nt = K >> 6;
  const int r7 = lr & 7;
  __bf16* Cd = C + (size_t)zsel * (size_t)M * ldc;
  stage(0, 0, kz);
  __syncthreads();
  int g = 0;
  #pragma unroll
  for (int mt = 0; mt < MT; ++mt){
    f32x4 acc[4][4] = {};
    for (int t = 0; t < nt; ++t){
      const int cur = g & 1;
      if (t + 1 < nt)        stage(cur ^ 1, mt*128,     kz + (t+1)*64);
      else if (mt + 1 < MT)  stage(cur ^ 1, (mt+1)*128, kz);
      #pragma unroll
      for (int kk = 0; kk < 2; ++kk){
        const int cs = ((kk*4 + lg) ^ r7) * 8;   // swizzled 16B slot
        bf16x8 af[4], bfv[4];
        #pragma unroll
        for (int mf = 0; mf < 4; ++mf)
          af[mf]  = *(const bf16x8*)&Als[cur][(wr*64 + mf*16 + lr)*64 + cs];
        #pragma unroll
        for (int nf = 0; nf < 4; ++nf)
          bfv[nf] = *(const bf16x8*)&Bls[cur][(wc*64 + nf*16 + lr)*64 + cs];
        #pragma unroll
        for (int mf = 0; mf < 4; ++mf)
          #pragma unroll
          for (int nf = 0; nf < 4; ++nf)
            acc[mf][nf] = mfma16x16x32(af[mf], bfv[nf], acc[mf][nf]);
      }
      __syncthreads();   // drains stage (issued this iter) + buffer reads
      ++g;
    }
    // ---- epilogue for m-tile mt (next tile's first slab already in LDS) ----
    const int m0 = mbase + mt*128;
    float rsp4[4][4];
    #pragma unroll
    for (int mf = 0; mf < 4; ++mf)
      #pragma unroll
      for (int r = 0; r < 4; ++r) rsp4[mf][r] = 0.0f;
    #pragma unroll
    for (int mf = 0; mf < 4; ++mf)
      #pragma unroll
      for (int nf = 0; nf < 4; ++nf)
        #pragma unroll
        for (int r = 0; r < 4; ++r){
          int row = m0 + wr*64 + mf*16 + lg*4 + r;
          int col = n0 + wc*64 + nf*16 + lr;
          float v = acc[mf][nf][r];
          if (EPI == 0) v += bias[col];
          if (EPI == 2) v = __expf(v * scale);
          Cd[(size_t)row * ldc + col] = (__bf16)v;
          if (RSUM) rsp4[mf][r] += v;
        }
    if (RSUM){
      #pragma unroll
      for (int mf = 0; mf < 4; ++mf)
        #pragma unroll
        for (int r = 0; r < 4; ++r)
          #pragma unroll
          for (int dl = 1; dl < 16; dl <<= 1)
            rsp4[mf][r] += __shfl_xor(rsp4[mf][r], dl);
      if (lr == 0){
        int cb = rbase + (n0 >> 6) + wc;
        #pragma unroll
        for (int mf = 0; mf < 4; ++mf)
          #pragma unroll
          for (int r = 0; r < 4; ++r)
            rsp[(size_t)cb * N_TOK + m0 + wr*64 + mf*16 + lg*4 + r] = rsp4[mf][r];
      }
    }
  }
}

// ---------------- V-projection split-K combine: vtb = p0 + p1 + bv[row] -----
__global__ __launch_bounds__(256) void k_vcomb(
    const __bf16* __restrict__ p, const float* __restrict__ bv,
    __bf16* __restrict__ vtb)
{
  int idx = blockIdx.x * 256 + threadIdx.x;   // 512*8192/8
  int row = idx >> 10;
  float b = bv[row];
  bf16x8 a = ((const bf16x8*)p)[idx];
  bf16x8 c = ((const bf16x8*)(p + (size_t)DMODEL * N_TOK))[idx];
  bf16x8 o;
  #pragma unroll
  for (int i = 0; i < 8; ++i)
    o[i] = (__bf16)((float)a[i] + (float)c[i] + b);
  ((bf16x8*)vtb)[idx] = o;
}

// ---------------- MLP head (fused rs-reduce + 4-partial combine + GEMM) -----
__global__ __launch_bounds__(256) void k_mlp(
    const __bf16* __restrict__ p00, const __bf16* __restrict__ p01,
    const __bf16* __restrict__ p10, const __bf16* __restrict__ p11,
    const float* __restrict__ rsp, const __bf16* __restrict__ W1t,
    const float* __restrict__ b1, const float* __restrict__ W2,
    const float* __restrict__ b2, float* __restrict__ out)
{
  __shared__ __bf16 Als[64][512];
  __shared__ float  red[4][64];
  __shared__ float  rsv[64];
  const int tid = threadIdx.x;
  const int w = tid >> 6, l = tid & 63;
  const int lr = l & 15, lg = l >> 4;
  const int m0 = blockIdx.x * 64;
  if (tid < 64){
    float s = 0.0f;
    #pragma unroll 8
    for (int j = 0; j < 128; ++j) s += rsp[(size_t)j * N_TOK + m0 + tid];
    rsv[tid] = s;
  }
  __syncthreads();
  #pragma unroll
  for (int i = 0; i < 16; ++i){
    int chunk = i*256 + tid;            // 0..4095
    int rl = chunk >> 6, c8 = chunk & 63;
    size_t off = (size_t)(m0 + rl) * 64 + c8;
    float inv = 1.0f / rsv[rl];
    bf16x8 a = ((const bf16x8*)p00)[off];
    bf16x8 b = ((const bf16x8*)p01)[off];
    bf16x8 c = ((const bf16x8*)p10)[off];
    bf16x8 d = ((const bf16x8*)p11)[off];
    bf16x8 o;
    #pragma unroll
    for (int j = 0; j < 8; ++j)
      o[j] = (__bf16)((((float)a[j] + (float)b[j]) + ((float)c[j] + (float)d[j])) * inv);
    *(bf16x8*)&Als[rl][c8*8] = o;
  }
  __syncthreads();
  f32x4 acc[4][4] = {};
  for (int t = 0; t < 16; ++t){
    bf16x8 af[4];
    #pragma unroll
    for (int mf2 = 0; mf2 < 4; ++mf2) af[mf2] = *(const bf16x8*)&Als[mf2*16 + lr][t*32 + lg*8];
    #pragma unroll
    for (int nf2 = 0; nf2 < 4; ++nf2){
      bf16x8 bfr = *(const bf16x8*)&W1t[(size_t)(w*64 + nf2*16 + lr)*DMODEL + t*32 + lg*8];
      #pragma unroll
      for (int mf2 = 0; mf2 < 4; ++mf2)
        acc[mf2][nf2] = mfma16x16x32(af[mf2], bfr, acc[mf2][nf2]);
    }
  }
  float part[4][4] = {};
  #pragma unroll
  for (int nf2 = 0; nf2 < 4; ++nf2){
    int col = w*64 + nf2*16 + lr;
    float bb = b1[col], w2v = W2[col];
    #pragma unroll
    for (int mf2 = 0; mf2 < 4; ++mf2)
      #pragma unroll
      for (int r = 0; r < 4; ++r){
        float h = acc[mf2][nf2][r] + bb;
        h = h > 0.0f ? h : 0.0f;
        part[mf2][r] += h * w2v;
      }
  }
  #pragma unroll
  for (int mf2 = 0; mf2 < 4; ++mf2)
    #pragma unroll
    for (int r = 0; r < 4; ++r)
      #pragma unroll
      for (int dl = 1; dl < 16; dl <<= 1)
        part[mf2][r] += __shfl_xor(part[mf2][r], dl);
  if (lr == 0){
    #pragma unroll
    for (int mf2 = 0; mf2 < 4; ++mf2)
      #pragma unroll
      for (int r = 0; r < 4; ++r)
        red[w][mf2*16 + lg*4 + r] = part[mf2][r];
  }
  __syncthreads();
  if (tid < 64)
    out[m0 + tid] = red[0][tid] + red[1][tid] + red[2][tid] + red[3][tid] + b2[0];
}

// ---------------- launcher ----------------
extern "C" void kernel_launch(void* const* d_in, const int* in_sizes, int n_in,
                              void* d_out, int out_size, void* d_ws, size_t ws_size,
                              hipStream_t stream)
{
  const float* x  = (const float*)d_in[0];
  const float* Wq = (const float*)d_in[1];
  const float* bq = (const float*)d_in[2];
  const float* Wk = (const float*)d_in[3];
  const float* bk = (const float*)d_in[4];
  const float* Wv = (const float*)d_in[5];
  const float* bv = (const float*)d_in[6];
  const float* W1 = (const float*)d_in[7];
  const float* b1 = (const float*)d_in[8];
  const float* W2 = (const float*)d_in[9];
  const float* b2 = (const float*)d_in[10];
  float* out = (float*)d_out;
  char* ws = (char*)d_ws;
  // workspace layout
  __bf16* xb   = (__bf16*)(ws + 0);          // 16 MB (dead after V GEMM)
  __bf16* qkb  = (__bf16*)(ws + 16777216);   // 16 MB [8192][1024] rows [q|k]
  __bf16* vtb  = (__bf16*)(ws + 33554432);   // 8 MB  V^T [512][8192]
  __bf16* wqkt = (__bf16*)(ws + 50331648);   // 2 MB  [Wq^T ; Wk^T]
  __bf16* wvt  = (__bf16*)(ws + 52428800);   // 1 MB
  __bf16* w1t  = (__bf16*)(ws + 53477376);   // 0.25 MB
  float*  bqk  = (float*)(ws + 53772288);    // 4 KB
  float*  rsp  = (float*)(ws + 54525952);    // 4 MB  [128][8192] partial row sums
  __bf16* Ph   = (__bf16*)(ws + 58720256);   // 64 MB  P half [8192][4096]
  __bf16* vpp  = (__bf16*)(ws + 58720256);   // V-proj partials (Ph region, early)
  // PV split-K partials (dead-region reuse)
  __bf16* p00  = (__bf16*)(ws + 0);          // xb region
  __bf16* p01  = (__bf16*)(ws + 8388608);
  __bf16* p10  = (__bf16*)(ws + 16777216);   // qkb region (dead after pexp1)
  __bf16* p11  = (__bf16*)(ws + 25165824);

  k_cvt<<<2048, 256, 0, stream>>>(x, xb, N_TOK*INDIM/4);
  k_prep<<<1024, 256, 0, stream>>>(Wq, Wk, Wv, W1, bq, bk, wqkt, wvt, w1t, bqk);

  // fused Q|K projection
  k_gemm<0,0,0,1><<<dim3(64, 8), 256, 0, stream>>>(xb, wqkt, bqk, qkb,
      N_TOK, 2*DMODEL, INDIM, INDIM, INDIM, 2*DMODEL, 0.f, nullptr, 0);
  // V^T split-K + combine
  k_gemm<3,0,0,1><<<dim3(4, 64, 2), 256, 0, stream>>>(wvt, xb, nullptr, vpp,
      DMODEL, N_TOK, INDIM/2, INDIM, INDIM, N_TOK, 0.f, nullptr, 0);
  k_vcomb<<<DMODEL*N_TOK/8/256, 256, 0, stream>>>(vpp, bv, vtb);

  const float scale = 0.04419417382415922f;  // 1/sqrt(512)
  const __bf16* Qm = qkb;            // lda 1024
  const __bf16* Km = qkb + DMODEL;   // ldb 1024
  // ---- half 0 ----
  k_gemm<2,1,1,4><<<512, 256, 0, stream>>>(Qm, Km, nullptr, Ph,
      N_TOK, NHALF, DMODEL, 2*DMODEL, 2*DMODEL, NHALF, scale, rsp, 0);
  k_gemm<3,2,0,1><<<512, 256, 0, stream>>>(Ph, vtb, nullptr, p00,
      N_TOK, DMODEL, NHALF/2, NHALF, N_TOK, DMODEL, 0.f, nullptr, 0);
  // ---- half 1 ----
  k_gemm<2,1,1,4><<<512, 256, 0, stream>>>(Qm, Km + (size_t)NHALF*2*DMODEL, nullptr, Ph,
      N_TOK, NHALF, DMODEL, 2*DMODEL, 2*DMODEL, NHALF, scale, rsp, 64);
  k_gemm<3,2,0,1><<<512, 256, 0, stream>>>(Ph, vtb + NHALF, nullptr, p10,
      N_TOK, DMODEL, NHALF/2, NHALF, N_TOK, DMODEL, 0.f, nullptr, 0);

  k_mlp<<<N_TOK/64, 256, 0, stream>>>(p00, p01, p10, p11, rsp,
      w1t, b1, W2, b2, out);

  (void)in_sizes; (void)n_in; (void)out_size; (void)ws_size;
}

// Round 22
// 253.156 us; speedup vs baseline: 1.2124x; 1.0081x over previous
//
#include <hip/hip_runtime.h>
#include <hip/hip_bf16.h>
#include <cstdint>
#include <cstddef>

typedef float  f32x4  __attribute__((ext_vector_type(4)));
typedef __bf16 bf16x8 __attribute__((ext_vector_type(8)));
typedef __bf16 bf16x4 __attribute__((ext_vector_type(4)));

#define N_TOK  8192
#define INDIM  1024
#define DMODEL 512
#define NHALF  4096   // key-split half for P materialization

__device__ __forceinline__ f32x4 mfma16x16x32(bf16x8 a, bf16x8 b, f32x4 c){
  return __builtin_amdgcn_mfma_f32_16x16x32_bf16(a, b, c, 0, 0, 0);
}

__device__ __forceinline__ void async_copy16(void* lds, const void* g){
  __builtin_amdgcn_global_load_lds((__attribute__((address_space(1))) void*)g,
                                   (__attribute__((address_space(3))) void*)lds,
                                   16, 0, 0);
}

// ---------------- fused prep: x->bf16 + 4 weight transposes + bias concat ----
__global__ void k_prep(const float* __restrict__ x,
                       const float* __restrict__ Wq, const float* __restrict__ Wk,
                       const float* __restrict__ Wv, const float* __restrict__ W1,
                       const float* __restrict__ bq, const float* __restrict__ bk,
                       __bf16* __restrict__ xb,
                       __bf16* __restrict__ wqkt, __bf16* __restrict__ wvt,
                       __bf16* __restrict__ w1t, float* __restrict__ bqk)
{
  const int XC  = N_TOK * INDIM / 4;           // 2097152 f32x4 chunks
  const int WQK = INDIM * DMODEL;              // 524288
  const int W1N = DMODEL * (DMODEL/2);         // 131072
  const int TOT = XC + 3*WQK + W1N + 2*DMODEL;
  int stride = gridDim.x * blockDim.x;
  for (int i = blockIdx.x * blockDim.x + threadIdx.x; i < TOT; i += stride){
    if (i < XC){
      f32x4 v = ((const f32x4*)x)[i];
      bf16x4 o;
      o[0]=(__bf16)v[0]; o[1]=(__bf16)v[1]; o[2]=(__bf16)v[2]; o[3]=(__bf16)v[3];
      ((bf16x4*)xb)[i] = o;
    } else if (i < XC + WQK){
      int j = i - XC; int k = j / DMODEL, n = j - k*DMODEL;
      wqkt[(size_t)n * INDIM + k] = (__bf16)Wq[j];
    } else if (i < XC + 2*WQK){
      int j = i - XC - WQK; int k = j / DMODEL, n = j - k*DMODEL;
      wqkt[(size_t)(DMODEL + n) * INDIM + k] = (__bf16)Wk[j];
    } else if (i < XC + 3*WQK){
      int j = i - XC - 2*WQK; int k = j / DMODEL, n = j - k*DMODEL;
      wvt[(size_t)n * INDIM + k] = (__bf16)Wv[j];
    } else if (i < XC + 3*WQK + W1N){
      int j = i - XC - 3*WQK; int k = j / (DMODEL/2), n = j - k*(DMODEL/2);
      w1t[(size_t)n * DMODEL + k] = (__bf16)W1[j];
    } else {
      int j = i - XC - 3*WQK - W1N;
      bqk[j] = (j < DMODEL) ? bq[j] : bk[j - DMODEL];
    }
  }
}

// ---------------- generalized GEMM: C[M,N] = A[M,K-chunk] @ Bt^T ------------
// 128x128 tile, BK=64, double-buffered 2-phase, swizzled LDS (R17-verified).
// MT: persistent m-tiles per block (pipeline never drains across m-tiles).
// EPI: 0 = +bias[col]; 2 = exp(scale*acc); 3 = plain.
// MAP: 0 = (x=m-group, y=n, z=K-chunk); 1 = xcd-chunked m-groups (pexp, MT=4,
//      grid 512); 2 = z = xcd>>2, n innermost (PV, grid 512).
// RSUM: fused per-(colblock,row) partial row sums from acc (deterministic).
template<int EPI, int MAP, int RSUM, int MT>
__global__ __launch_bounds__(256) void k_gemm(
    const __bf16* __restrict__ A, const __bf16* __restrict__ Bt,
    const float* __restrict__ bias, __bf16* __restrict__ C,
    int M, int N, int K, int lda, int ldb, int ldc, float scale,
    float* __restrict__ rsp, int rbase)
{
  __shared__ __bf16 Als[2][128*64];   // 32 KB
  __shared__ __bf16 Bls[2][128*64];   // 32 KB
  const int tid = threadIdx.x;
  const int w = tid >> 6, l = tid & 63;
  const int lr = l & 15, lg = l >> 4;
  const int wr = w >> 1, wc = w & 1;
  int blockm, n0, kz, zsel;
  if (MAP == 0){
    blockm = blockIdx.x; n0 = blockIdx.y * 128; zsel = blockIdx.z; kz = zsel * K;
  } else if (MAP == 1){
    int lin = blockIdx.x, xcd = lin & 7, idx = lin >> 3;   // idx 0..63
    blockm = xcd*2 + (idx & 1); n0 = (idx >> 1) * 128; zsel = 0; kz = 0;
  } else {
    int lin = blockIdx.x, xcd = lin & 7, i = lin >> 3;
    zsel = xcd >> 2; kz = zsel * K;
    blockm = (xcd & 3)*16 + (i >> 2); n0 = (i & 3) * 128;
  }
  const int mbase = blockm * (128 * MT);
  const int srow = w*8 + (l >> 3);
  const int scol = ((l & 7) ^ (l >> 3)) * 8;

  auto stage = [&](int b, int moff, int kk){
    #pragma unroll
    for (int ro = 0; ro < 4; ++ro)
      async_copy16((char*)&Als[b][0] + ro*4096 + w*1024,
                   A  + (size_t)(mbase + moff + ro*32 + srow) * lda + kk + scol);
    #pragma unroll
    for (int ro = 0; ro < 4; ++ro)
      async_copy16((char*)&Bls[b][0] + ro*4096 + w*1024,
                   Bt + (size_t)(n0 + ro*32 + srow) * ldb + kk + scol);
  };

  const int nt = K >> 6;
  const int r7 = lr & 7;
  __bf16* Cd = C + (size_t)zsel * (size_t)M * ldc;
  stage(0, 0, kz);
  __syncthreads();
  int g = 0;
  #pragma unroll
  for (int mt = 0; mt < MT; ++mt){
    f32x4 acc[4][4] = {};
    for (int t = 0; t < nt; ++t){
      const int cur = g & 1;
      if (t + 1 < nt)        stage(cur ^ 1, mt*128,     kz + (t+1)*64);
      else if (mt + 1 < MT)  stage(cur ^ 1, (mt+1)*128, kz);
      #pragma unroll
      for (int kk = 0; kk < 2; ++kk){
        const int cs = ((kk*4 + lg) ^ r7) * 8;   // swizzled 16B slot
        bf16x8 af[4], bfv[4];
        #pragma unroll
        for (int mf = 0; mf < 4; ++mf)
          af[mf]  = *(const bf16x8*)&Als[cur][(wr*64 + mf*16 + lr)*64 + cs];
        #pragma unroll
        for (int nf = 0; nf < 4; ++nf)
          bfv[nf] = *(const bf16x8*)&Bls[cur][(wc*64 + nf*16 + lr)*64 + cs];
        #pragma unroll
        for (int mf = 0; mf < 4; ++mf)
          #pragma unroll
          for (int nf = 0; nf < 4; ++nf)
            acc[mf][nf] = mfma16x16x32(af[mf], bfv[nf], acc[mf][nf]);
      }
      __syncthreads();
      ++g;
    }
    // ---- epilogue for m-tile mt ----
    const int m0 = mbase + mt*128;
    float rsp4[4][4];
    #pragma unroll
    for (int mf = 0; mf < 4; ++mf)
      #pragma unroll
      for (int r = 0; r < 4; ++r) rsp4[mf][r] = 0.0f;
    #pragma unroll
    for (int mf = 0; mf < 4; ++mf)
      #pragma unroll
      for (int nf = 0; nf < 4; ++nf)
        #pragma unroll
        for (int r = 0; r < 4; ++r){
          int row = m0 + wr*64 + mf*16 + lg*4 + r;
          int col = n0 + wc*64 + nf*16 + lr;
          float v = acc[mf][nf][r];
          if (EPI == 0) v += bias[col];
          if (EPI == 2) v = __expf(v * scale);
          Cd[(size_t)row * ldc + col] = (__bf16)v;
          if (RSUM) rsp4[mf][r] += v;
        }
    if (RSUM){
      #pragma unroll
      for (int mf = 0; mf < 4; ++mf)
        #pragma unroll
        for (int r = 0; r < 4; ++r)
          #pragma unroll
          for (int dl = 1; dl < 16; dl <<= 1)
            rsp4[mf][r] += __shfl_xor(rsp4[mf][r], dl);
      if (lr == 0){
        int cb = rbase + (n0 >> 6) + wc;
        #pragma unroll
        for (int mf = 0; mf < 4; ++mf)
          #pragma unroll
          for (int r = 0; r < 4; ++r)
            rsp[(size_t)cb * N_TOK + m0 + wr*64 + mf*16 + lg*4 + r] = rsp4[mf][r];
      }
    }
  }
}

// ---------------- V-projection split-K combine: vtb = p0 + p1 + bv[row] -----
__global__ __launch_bounds__(256) void k_vcomb(
    const __bf16* __restrict__ p, const float* __restrict__ bv,
    __bf16* __restrict__ vtb)
{
  int idx = blockIdx.x * 256 + threadIdx.x;   // 512*8192/8
  int row = idx >> 10;
  float b = bv[row];
  bf16x8 a = ((const bf16x8*)p)[idx];
  bf16x8 c = ((const bf16x8*)(p + (size_t)DMODEL * N_TOK))[idx];
  bf16x8 o;
  #pragma unroll
  for (int i = 0; i < 8; ++i)
    o[i] = (__bf16)((float)a[i] + (float)c[i] + b);
  ((bf16x8*)vtb)[idx] = o;
}

// ---------------- MLP head (fused rs-reduce + 4-partial combine + GEMM) -----
__global__ __launch_bounds__(256) void k_mlp(
    const __bf16* __restrict__ p00, const __bf16* __restrict__ p01,
    const __bf16* __restrict__ p10, const __bf16* __restrict__ p11,
    const float* __restrict__ rsp, const __bf16* __restrict__ W1t,
    const float* __restrict__ b1, const float* __restrict__ W2,
    const float* __restrict__ b2, float* __restrict__ out)
{
  __shared__ __bf16 Als[64][512];
  __shared__ float  red[4][64];
  __shared__ float  rsv[64];
  const int tid = threadIdx.x;
  const int w = tid >> 6, l = tid & 63;
  const int lr = l & 15, lg = l >> 4;
  const int m0 = blockIdx.x * 64;
  if (tid < 64){
    float s = 0.0f;
    #pragma unroll 8
    for (int j = 0; j < 128; ++j) s += rsp[(size_t)j * N_TOK + m0 + tid];
    rsv[tid] = s;
  }
  __syncthreads();
  #pragma unroll
  for (int i = 0; i < 16; ++i){
    int chunk = i*256 + tid;            // 0..4095
    int rl = chunk >> 6, c8 = chunk & 63;
    size_t off = (size_t)(m0 + rl) * 64 + c8;
    float inv = 1.0f / rsv[rl];
    bf16x8 a = ((const bf16x8*)p00)[off];
    bf16x8 b = ((const bf16x8*)p01)[off];
    bf16x8 c = ((const bf16x8*)p10)[off];
    bf16x8 d = ((const bf16x8*)p11)[off];
    bf16x8 o;
    #pragma unroll
    for (int j = 0; j < 8; ++j)
      o[j] = (__bf16)((((float)a[j] + (float)b[j]) + ((float)c[j] + (float)d[j])) * inv);
    *(bf16x8*)&Als[rl][c8*8] = o;
  }
  __syncthreads();
  f32x4 acc[4][4] = {};
  for (int t = 0; t < 16; ++t){
    bf16x8 af[4];
    #pragma unroll
    for (int mf2 = 0; mf2 < 4; ++mf2) af[mf2] = *(const bf16x8*)&Als[mf2*16 + lr][t*32 + lg*8];
    #pragma unroll
    for (int nf2 = 0; nf2 < 4; ++nf2){
      bf16x8 bfr = *(const bf16x8*)&W1t[(size_t)(w*64 + nf2*16 + lr)*DMODEL + t*32 + lg*8];
      #pragma unroll
      for (int mf2 = 0; mf2 < 4; ++mf2)
        acc[mf2][nf2] = mfma16x16x32(af[mf2], bfr, acc[mf2][nf2]);
    }
  }
  float part[4][4] = {};
  #pragma unroll
  for (int nf2 = 0; nf2 < 4; ++nf2){
    int col = w*64 + nf2*16 + lr;
    float bb = b1[col], w2v = W2[col];
    #pragma unroll
    for (int mf2 = 0; mf2 < 4; ++mf2)
      #pragma unroll
      for (int r = 0; r < 4; ++r){
        float h = acc[mf2][nf2][r] + bb;
        h = h > 0.0f ? h : 0.0f;
        part[mf2][r] += h * w2v;
      }
  }
  #pragma unroll
  for (int mf2 = 0; mf2 < 4; ++mf2)
    #pragma unroll
    for (int r = 0; r < 4; ++r)
      #pragma unroll
      for (int dl = 1; dl < 16; dl <<= 1)
        part[mf2][r] += __shfl_xor(part[mf2][r], dl);
  if (lr == 0){
    #pragma unroll
    for (int mf2 = 0; mf2 < 4; ++mf2)
      #pragma unroll
      for (int r = 0; r < 4; ++r)
        red[w][mf2*16 + lg*4 + r] = part[mf2][r];
  }
  __syncthreads();
  if (tid < 64)
    out[m0 + tid] = red[0][tid] + red[1][tid] + red[2][tid] + red[3][tid] + b2[0];
}

// ---------------- launcher ----------------
extern "C" void kernel_launch(void* const* d_in, const int* in_sizes, int n_in,
                              void* d_out, int out_size, void* d_ws, size_t ws_size,
                              hipStream_t stream)
{
  const float* x  = (const float*)d_in[0];
  const float* Wq = (const float*)d_in[1];
  const float* bq = (const float*)d_in[2];
  const float* Wk = (const float*)d_in[3];
  const float* bk = (const float*)d_in[4];
  const float* Wv = (const float*)d_in[5];
  const float* bv = (const float*)d_in[6];
  const float* W1 = (const float*)d_in[7];
  const float* b1 = (const float*)d_in[8];
  const float* W2 = (const float*)d_in[9];
  const float* b2 = (const float*)d_in[10];
  float* out = (float*)d_out;
  char* ws = (char*)d_ws;
  // workspace layout
  __bf16* xb   = (__bf16*)(ws + 0);          // 16 MB (dead after V GEMM)
  __bf16* qkb  = (__bf16*)(ws + 16777216);   // 16 MB [8192][1024] rows [q|k]
  __bf16* vtb  = (__bf16*)(ws + 33554432);   // 8 MB  V^T [512][8192]
  __bf16* wqkt = (__bf16*)(ws + 50331648);   // 2 MB  [Wq^T ; Wk^T]
  __bf16* wvt  = (__bf16*)(ws + 52428800);   // 1 MB
  __bf16* w1t  = (__bf16*)(ws + 53477376);   // 0.25 MB
  float*  bqk  = (float*)(ws + 53772288);    // 4 KB
  float*  rsp  = (float*)(ws + 54525952);    // 4 MB  [128][8192] partial row sums
  __bf16* Ph   = (__bf16*)(ws + 58720256);   // 64 MB  P half [8192][4096]
  __bf16* vpp  = (__bf16*)(ws + 58720256);   // V-proj partials (Ph region, early)
  // PV split-K partials (dead-region reuse)
  __bf16* p00  = (__bf16*)(ws + 0);          // xb region
  __bf16* p01  = (__bf16*)(ws + 8388608);
  __bf16* p10  = (__bf16*)(ws + 16777216);   // qkb region (dead after pexp1)
  __bf16* p11  = (__bf16*)(ws + 25165824);

  k_prep<<<2048, 256, 0, stream>>>(x, Wq, Wk, Wv, W1, bq, bk,
                                   xb, wqkt, wvt, w1t, bqk);

  // fused Q|K projection
  k_gemm<0,0,0,1><<<dim3(64, 8), 256, 0, stream>>>(xb, wqkt, bqk, qkb,
      N_TOK, 2*DMODEL, INDIM, INDIM, INDIM, 2*DMODEL, 0.f, nullptr, 0);
  // V^T split-K + combine
  k_gemm<3,0,0,1><<<dim3(4, 64, 2), 256, 0, stream>>>(wvt, xb, nullptr, vpp,
      DMODEL, N_TOK, INDIM/2, INDIM, INDIM, N_TOK, 0.f, nullptr, 0);
  k_vcomb<<<DMODEL*N_TOK/8/256, 256, 0, stream>>>(vpp, bv, vtb);

  const float scale = 0.04419417382415922f;  // 1/sqrt(512)
  const __bf16* Qm = qkb;            // lda 1024
  const __bf16* Km = qkb + DMODEL;   // ldb 1024
  // ---- half 0 ----
  k_gemm<2,1,1,4><<<512, 256, 0, stream>>>(Qm, Km, nullptr, Ph,
      N_TOK, NHALF, DMODEL, 2*DMODEL, 2*DMODEL, NHALF, scale, rsp, 0);
  k_gemm<3,2,0,1><<<512, 256, 0, stream>>>(Ph, vtb, nullptr, p00,
      N_TOK, DMODEL, NHALF/2, NHALF, N_TOK, DMODEL, 0.f, nullptr, 0);
  // ---- half 1 ----
  k_gemm<2,1,1,4><<<512, 256, 0, stream>>>(Qm, Km + (size_t)NHALF*2*DMODEL, nullptr, Ph,
      N_TOK, NHALF, DMODEL, 2*DMODEL, 2*DMODEL, NHALF, scale, rsp, 64);
  k_gemm<3,2,0,1><<<512, 256, 0, stream>>>(Ph, vtb + NHALF, nullptr, p10,
      N_TOK, DMODEL, NHALF/2, NHALF, N_TOK, DMODEL, 0.f, nullptr, 0);

  k_mlp<<<N_TOK/64, 256, 0, stream>>>(p00, p01, p10, p11, rsp,
      w1t, b1, W2, b2, out);

  (void)in_sizes; (void)n_in; (void)out_size; (void)ws_size;
}